// Round 3
// baseline (14550.262 us; speedup 1.0000x reference)
//
#include <hip/hip_runtime.h>
#include <hip/hip_fp16.h>

// CapsNet dynamic routing, B=256 N=2048 C=10 D_IN=8 D_OUT=16, ROUTING_ITERS=3.
// R2 (resubmit after infra timeout): latency-bound fix. W staged via LDS (coalesced),
// c-in-LDS (fp16) instead of LDS s-accumulator (no LDS atomics), s accumulated in
// 20 regs/lane with jo-split, vT transposed v for coalesced per-lane reads,
// 12 waves/CU (46 KiB LDS).
// ws: partials [128][160][256] f32 (20.97 MB) + vT0 + vsumT = 21,299,200 B.

#define B_SZ  256
#define N_SZ  2048
#define C_SZ  10
#define DIN   8
#define DOUT  16
#define JO    (C_SZ*DOUT)   // 160
#define IC    16            // i's per chunk (per block)
#define NCH   (N_SZ/IC)     // 128 chunks
#define IPR   8             // i's staged per round (2 rounds)
#define BSUB  32            // b's per block
#define NBG   (B_SZ/BSUB)   // 8 b-groups
#define JOW   20            // jo's owned per (wave,half) unit in pass 2

__device__ __forceinline__ void softmax10(float* a) {
    float m = a[0];
#pragma unroll
    for (int j = 1; j < C_SZ; ++j) m = fmaxf(m, a[j]);
    float s = 0.f;
#pragma unroll
    for (int j = 0; j < C_SZ; ++j) { a[j] = __expf(a[j] - m); s += a[j]; }
    float inv = 1.f / s;
#pragma unroll
    for (int j = 0; j < C_SZ; ++j) a[j] *= inv;
}

// have_v=0: iter-0 (uniform c, scale applied in reduce)
// have_v=1: agreement vs vT (iter-1: vT0; iter-2: vT0+vT1 presummed — exact since
//           b_ij = uh.v0 + uh.v1 = uh.(v0+v1))
__global__ __launch_bounds__(256, 3)
void caps_phase(const float* __restrict__ u, const float* __restrict__ W,
                const float* __restrict__ vT, float* __restrict__ s_part, int have_v)
{
    __shared__ __align__(16) float Wl[IPR*JO*DIN];   // 40960 B, one round's W
    __shared__ __half cl[IPR][C_SZ][BSUB];           // 5120 B softmax coeffs
    const int tid  = threadIdx.x;
    const int lane = tid & 63;
    const int wid  = tid >> 6;          // 0..3
    const int bb   = lane & 31;         // b within block
    const int ih   = lane >> 5;         // half-wave
    const int unit = wid*2 + ih;        // 0..7: owns 1 i per round (pass1), 20 jo (pass2)
    // XCD swizzle: the 8 bg-siblings of a chunk are at stride 128 -> same bid%8 -> same XCD,
    // so the chunk's 80 KiB W slice is fetched into ONE XCD's L2.
    const int bg = blockIdx.x >> 7;     // 0..7
    const int ch = blockIdx.x & 127;    // 0..127
    const int b  = bg*BSUB + bb;
    const int jo0 = unit*JOW;

    float sreg[JOW];
#pragma unroll
    for (int k = 0; k < JOW; ++k) sreg[k] = 0.f;

    for (int r = 0; r < 2; ++r) {
        // ---- stage this round's W (8 i x 160 jo x 8 n = 40960 B, contiguous) ----
        const float* wsrc = W + ((size_t)(ch*IC + r*IPR))*(C_SZ*DOUT*DIN);
        __syncthreads();                               // protect Wl from prev round readers
#pragma unroll
        for (int k = 0; k < 10; ++k)
            ((float4*)Wl)[k*256 + tid] = ((const float4*)wsrc)[k*256 + tid];
        __syncthreads();

        // ---- pass 1: agreement + softmax for my i (one per unit) -> cl (fp16) ----
        if (have_v) {
            const int il = unit;                       // local i slot this round
            const float* up = u + ((size_t)b*N_SZ + ch*IC + r*IPR + il)*DIN;
            const float4 ua = ((const float4*)up)[0];
            const float4 ub = ((const float4*)up)[1];
            const float* wbase = Wl + il*(JO*DIN);     // uniform per half-wave: 2-addr broadcast
            float a[C_SZ];
#pragma unroll
            for (int j = 0; j < C_SZ; ++j) {
                float acc = 0.f;
#pragma unroll
                for (int o = 0; o < DOUT; ++o) {
                    const int jo = j*DOUT + o;
                    const float4 w0 = ((const float4*)(wbase + jo*DIN))[0];
                    const float4 w1 = ((const float4*)(wbase + jo*DIN))[1];
                    float uh = w0.x*ua.x;
                    uh = fmaf(w0.y, ua.y, uh); uh = fmaf(w0.z, ua.z, uh); uh = fmaf(w0.w, ua.w, uh);
                    uh = fmaf(w1.x, ub.x, uh); uh = fmaf(w1.y, ub.y, uh);
                    uh = fmaf(w1.z, ub.z, uh); uh = fmaf(w1.w, ub.w, uh);
                    acc = fmaf(uh, vT[jo*B_SZ + b], acc);   // coalesced 32-run, L2-hot
                }
                a[j] = acc;
            }
            softmax10(a);
#pragma unroll
            for (int j = 0; j < C_SZ; ++j) cl[unit][j][bb] = __float2half(a[j]);
        }
        __syncthreads();                               // cl ready for pass 2

        // ---- pass 2: jo-split; s[jo0..jo0+19] += sum_i c[i]*uh[i,jo] ----
        const float* up2 = u + ((size_t)b*N_SZ + ch*IC + r*IPR)*DIN;
        float4 na = ((const float4*)up2)[0];           // software-pipelined u row
        float4 nb = ((const float4*)up2)[1];
#pragma unroll 1
        for (int il = 0; il < IPR; ++il) {
            const float4 ca = na, cb = nb;
            if (il < IPR-1) {
                na = ((const float4*)(up2 + (il+1)*DIN))[0];
                nb = ((const float4*)(up2 + (il+1)*DIN))[1];
            }
            const float* wbase = Wl + il*(JO*DIN);
#pragma unroll
            for (int k = 0; k < JOW; ++k) {
                const int jo = jo0 + k;
                const float4 w0 = ((const float4*)(wbase + jo*DIN))[0];
                const float4 w1 = ((const float4*)(wbase + jo*DIN))[1];
                float uh = w0.x*ca.x;
                uh = fmaf(w0.y, ca.y, uh); uh = fmaf(w0.z, ca.z, uh); uh = fmaf(w0.w, ca.w, uh);
                uh = fmaf(w1.x, cb.x, uh); uh = fmaf(w1.y, cb.y, uh);
                uh = fmaf(w1.z, cb.z, uh); uh = fmaf(w1.w, cb.w, uh);
                const float c = have_v ? __half2float(cl[il][jo>>4][bb]) : 1.f;
                sreg[k] = fmaf(c, uh, sreg[k]);
            }
        }
    }
    // ---- deposit partial: [ch][jo][b], coalesced 32-runs per half-wave ----
    float* outp = s_part + (size_t)ch*(JO*B_SZ);
#pragma unroll
    for (int k = 0; k < JOW; ++k) outp[(jo0+k)*B_SZ + b] = sreg[k];
}

// Sum the 128 chunk partials; overwrite chunk-0 slice as s_sum[jo][b]. Coalesced.
__global__ __launch_bounds__(256)
void caps_reduceA(float* __restrict__ s_part, float pre_scale)
{
    const int idx = blockIdx.x*256 + threadIdx.x;      // < 40960
    float s = 0.f;
    for (int c = 0; c < NCH; ++c) s += s_part[(size_t)c*(JO*B_SZ) + idx];
    s_part[idx] = s * pre_scale;
}

// squash per (b,j); optionally write vT_out = v (+ vT_prev), or final outputs.
__global__ __launch_bounds__(256)
void caps_squash(const float* __restrict__ s_sum, const float* __restrict__ vT_prev,
                 float* __restrict__ vT_out, float* __restrict__ out_v,
                 float* __restrict__ out_logit)
{
    const int t = blockIdx.x*256 + threadIdx.x;        // < 2560
    const int b = t / C_SZ, j = t % C_SZ;
    float sv[DOUT]; float n2 = 0.f;
#pragma unroll
    for (int o = 0; o < DOUT; ++o) {
        const float x = s_sum[(j*DOUT + o)*B_SZ + b];
        sv[o] = x; n2 = fmaf(x, x, n2);
    }
    const float norm  = sqrtf(n2);
    const float nc    = fmaxf(norm, 1e-7f);
    const float scale = 1.f - 1.f/(1.f + nc*nc);       // matches reference (clamped norm)
    const float inv   = scale / nc;
    if (vT_out) {
#pragma unroll
        for (int o = 0; o < DOUT; ++o) {
            const float v = sv[o]*inv;
            const float p = vT_prev ? vT_prev[(j*DOUT + o)*B_SZ + b] : 0.f;
            vT_out[(j*DOUT + o)*B_SZ + b] = v + p;     // iter-1 writes v0+v1 directly
        }
    }
    if (out_v) {
        float q = 0.f;
#pragma unroll
        for (int o = 0; o < DOUT; ++o) {
            const float v = sv[o]*inv;
            out_v[(size_t)b*JO + j*DOUT + o] = v;      // [256,10,16] coalesced-ish
            q = fmaf(v, v, q);
        }
        out_logit[t] = sqrtf(q);                       // [256,10]
    }
}

extern "C" void kernel_launch(void* const* d_in, const int* in_sizes, int n_in,
                              void* d_out, int out_size, void* d_ws, size_t ws_size,
                              hipStream_t stream)
{
    const float* u = (const float*)d_in[0];   // [256,2048,8]
    const float* W = (const float*)d_in[1];   // [2048,10,16,8]
    float* out_v     = (float*)d_out;         // [256,10,16]
    float* out_logit = out_v + B_SZ*JO;       // [256,10]

    float* s_part = (float*)d_ws;             // [128][160][256] f32; chunk0 doubles as s_sum
    float* vT0    = s_part + (size_t)NCH*JO*B_SZ;
    float* vsumT  = vT0 + JO*B_SZ;

    dim3 blk(256), gphase(NCH*NBG), gred(JO*B_SZ/256), gsq(B_SZ*C_SZ/256);

    // iter 0: uniform c (softmax of zeros = 1/10 -> fold into pre_scale)
    caps_phase<<<gphase, blk, 0, stream>>>(u, W, nullptr, s_part, 0);
    caps_reduceA<<<gred, blk, 0, stream>>>(s_part, 0.1f);
    caps_squash<<<gsq, blk, 0, stream>>>(s_part, nullptr, vT0, nullptr, nullptr);
    // iter 1: b = uh.v0
    caps_phase<<<gphase, blk, 0, stream>>>(u, W, vT0, s_part, 1);
    caps_reduceA<<<gred, blk, 0, stream>>>(s_part, 1.0f);
    caps_squash<<<gsq, blk, 0, stream>>>(s_part, vT0, vsumT, nullptr, nullptr);
    // iter 2: b = uh.(v0+v1); final squash -> outputs
    caps_phase<<<gphase, blk, 0, stream>>>(u, W, vsumT, s_part, 1);
    caps_reduceA<<<gred, blk, 0, stream>>>(s_part, 1.0f);
    caps_squash<<<gsq, blk, 0, stream>>>(s_part, nullptr, nullptr, out_v, out_logit);
}

// Round 4
// 1888.639 us; speedup vs baseline: 7.7041x; 7.7041x over previous
//
#include <hip/hip_runtime.h>

// CapsNet dynamic routing, B=256 N=2048 C=10 D_IN=8 D_OUT=16, ROUTING_ITERS=3.
// R4: R1 skeleton (proven sane: 20 MB write / 54 MB fetch) + ONE fix: W staged
// through LDS with coalesced float4 loads (R1 was scalar-cache-thrash-bound).
// All per-thread arrays statically indexed; no fp16, no unroll-1 pipelines,
// no register jo-split (R2's variants of those produced 19 GB/launch of
// phantom scratch traffic). Half-wave i-split: lanes 0-31 / 32-63 handle
// adjacent i's -> 2-addr LDS broadcasts (free) and shared u cache lines.
// LDS 60 KiB/block -> 2 blocks/CU; grid 1024 = exactly 2 full waves of 512.
// ws: s_part [128][160][256] f32 (20.97 MB) + vT0 + vsumT (160 KB each).

#define B_SZ  256
#define N_SZ  2048
#define C_SZ  10
#define DIN   8
#define DOUT  16
#define JO    (C_SZ*DOUT)     // 160
#define IC    16              // i's per chunk
#define NCH   (N_SZ/IC)       // 128 chunks
#define IPR   8               // i's staged per round (2 rounds)
#define WROW  (JO*DIN)        // 1280 floats per i
#define BSUB  32              // b's per block
#define NBG   (B_SZ/BSUB)     // 8 b-groups

__device__ __forceinline__ void softmax10(float* a) {
    float m = a[0];
#pragma unroll
    for (int j = 1; j < C_SZ; ++j) m = fmaxf(m, a[j]);
    float s = 0.f;
#pragma unroll
    for (int j = 0; j < C_SZ; ++j) { a[j] = __expf(a[j] - m); s += a[j]; }
    float inv = 1.f / s;
#pragma unroll
    for (int j = 0; j < C_SZ; ++j) a[j] *= inv;
}

// have_v=0: iter-0 (uniform c; 1/10 folded into reduce's pre_scale)
// have_v=1: agreement vs vT (iter-1: vT0; iter-2: vT0+vT1 presummed — exact since
//           b_ij accumulates: softmax(uh.v0 + uh.v1) = softmax(uh.(v0+v1)))
__global__ __launch_bounds__(256, 2)
void caps_phase(const float* __restrict__ u, const float* __restrict__ W,
                const float* __restrict__ vT, float* __restrict__ s_part, int have_v)
{
    __shared__ __align__(16) float Wl[IPR*WROW];   // 40960 B: one round's W
    __shared__ float slds[JO*BSUB];                // 20480 B: s accumulator [jo][b]
    const int tid  = threadIdx.x;
    const int lane = tid & 63;
    const int wid  = tid >> 6;        // 0..3
    const int bb   = lane & 31;       // b within block
    const int ih   = lane >> 5;       // half-wave selects i within pair
    const int il   = wid*2 + ih;      // 0..7: i-slot within the staged round
    // bg in HIGH bits: the 8 blocks sharing a W chunk sit at bid stride 128 == 0 (mod 8)
    // -> same XCD -> chunk fetched into one L2.
    const int bg   = blockIdx.x >> 7; // 0..7
    const int ch   = blockIdx.x & 127;
    const int b    = bg*BSUB + bb;

#pragma unroll
    for (int k = 0; k < 5; ++k)                     // 5120 floats = 1280 float4
        ((float4*)slds)[k*256 + tid] = float4{0.f,0.f,0.f,0.f};

    for (int r = 0; r < 2; ++r) {
        __syncthreads();   // slds init visible (r=0) / prior-round Wl readers done (r=1)
        // ---- stage round's W: 8 i x 1280 floats = 40960 B contiguous, coalesced ----
        const float* wsrc = W + (size_t)(ch*IC + r*IPR)*WROW;
#pragma unroll
        for (int k = 0; k < 10; ++k)
            ((float4*)Wl)[k*256 + tid] = ((const float4*)wsrc)[k*256 + tid];
        __syncthreads();

        const int ig = ch*IC + r*IPR + il;                    // this lane's i
        const float* up = u + ((size_t)b*N_SZ + ig)*DIN;      // ih-halves share 64B lines
        const float4 ua = ((const float4*)up)[0];
        const float4 ub = ((const float4*)up)[1];
        const float* wbase = Wl + il*WROW;                    // 2 addrs/wave -> free bcast

        float c[C_SZ];
        if (have_v) {
            // ---- pass 1: agreement logits, per-lane softmax ----
#pragma unroll
            for (int j = 0; j < C_SZ; ++j) {
                float acc = 0.f;
#pragma unroll
                for (int o = 0; o < DOUT; ++o) {
                    const int jo = j*DOUT + o;
                    const float4 w0 = ((const float4*)(wbase + jo*DIN))[0];
                    const float4 w1 = ((const float4*)(wbase + jo*DIN))[1];
                    float uh = w0.x*ua.x;
                    uh = fmaf(w0.y, ua.y, uh); uh = fmaf(w0.z, ua.z, uh); uh = fmaf(w0.w, ua.w, uh);
                    uh = fmaf(w1.x, ub.x, uh); uh = fmaf(w1.y, ub.y, uh);
                    uh = fmaf(w1.z, ub.z, uh); uh = fmaf(w1.w, ub.w, uh);
                    acc = fmaf(uh, vT[jo*B_SZ + b], acc);     // 128B coalesced, L2-hot
                }
                c[j] = acc;
            }
            softmax10(c);                                     // per-lane, no divergence
        }
        // ---- pass 2: s[jo][b] += c[j] * uh[jo]  (recompute uh from LDS) ----
#pragma unroll
        for (int j = 0; j < C_SZ; ++j) {
            const float cj = have_v ? c[j] : 1.f;
#pragma unroll
            for (int o = 0; o < DOUT; ++o) {
                const int jo = j*DOUT + o;
                const float4 w0 = ((const float4*)(wbase + jo*DIN))[0];
                const float4 w1 = ((const float4*)(wbase + jo*DIN))[1];
                float uh = w0.x*ua.x;
                uh = fmaf(w0.y, ua.y, uh); uh = fmaf(w0.z, ua.z, uh); uh = fmaf(w0.w, ua.w, uh);
                uh = fmaf(w1.x, ub.x, uh); uh = fmaf(w1.y, ub.y, uh);
                uh = fmaf(w1.z, ub.z, uh); uh = fmaf(w1.w, ub.w, uh);
                // swizzled row: 32 lanes -> 32 banks; ih-halves collide on the same
                // cell by design (they carry different i's) — atomic handles it.
                atomicAdd(&slds[jo*BSUB + (bb ^ (jo & 31))], cj*uh);
            }
        }
    }
    __syncthreads();
    // ---- deposit partial [ch][jo][bg*32 .. +32], coalesced 128 B runs ----
    float* outp = s_part + (size_t)ch*(JO*B_SZ) + bg*BSUB;
    for (int k = tid; k < JO*BSUB; k += 256) {
        const int jo = k >> 5, b2 = k & 31;
        outp[jo*B_SZ + b2] = slds[jo*BSUB + (b2 ^ (jo & 31))];
    }
}

// Sum the 128 chunk partials; overwrite chunk-0 slice as s_sum[jo][b]. Coalesced.
__global__ __launch_bounds__(256)
void caps_reduceA(float* __restrict__ s_part, float pre_scale)
{
    const int idx = blockIdx.x*256 + threadIdx.x;      // < 40960
    float s = 0.f;
    for (int c = 0; c < NCH; ++c) s += s_part[(size_t)c*(JO*B_SZ) + idx];
    s_part[idx] = s * pre_scale;
}

// squash per (b,j); write vT_out = v (+ vT_prev), or final outputs.
__global__ __launch_bounds__(256)
void caps_squash(const float* __restrict__ s_sum, const float* __restrict__ vT_prev,
                 float* __restrict__ vT_out, float* __restrict__ out_v,
                 float* __restrict__ out_logit)
{
    const int t = blockIdx.x*256 + threadIdx.x;        // < 2560
    const int b = t / C_SZ, j = t % C_SZ;
    float sv[DOUT]; float n2 = 0.f;
#pragma unroll
    for (int o = 0; o < DOUT; ++o) {
        const float x = s_sum[(j*DOUT + o)*B_SZ + b];
        sv[o] = x; n2 = fmaf(x, x, n2);
    }
    const float norm  = sqrtf(n2);
    const float nc    = fmaxf(norm, 1e-7f);
    const float scale = 1.f - 1.f/(1.f + nc*nc);       // matches reference
    const float inv   = scale / nc;
    if (vT_out) {
#pragma unroll
        for (int o = 0; o < DOUT; ++o) {
            const float v = sv[o]*inv;
            const float p = vT_prev ? vT_prev[(j*DOUT + o)*B_SZ + b] : 0.f;
            vT_out[(j*DOUT + o)*B_SZ + b] = v + p;     // iter-1 writes v0+v1 directly
        }
    }
    if (out_v) {
        float q = 0.f;
#pragma unroll
        for (int o = 0; o < DOUT; ++o) {
            const float v = sv[o]*inv;
            out_v[(size_t)b*JO + j*DOUT + o] = v;      // [256,10,16]
            q = fmaf(v, v, q);
        }
        out_logit[t] = sqrtf(q);                       // [256,10]
    }
}

extern "C" void kernel_launch(void* const* d_in, const int* in_sizes, int n_in,
                              void* d_out, int out_size, void* d_ws, size_t ws_size,
                              hipStream_t stream)
{
    const float* u = (const float*)d_in[0];   // [256,2048,8]
    const float* W = (const float*)d_in[1];   // [2048,10,16,8]
    float* out_v     = (float*)d_out;         // [256,10,16]
    float* out_logit = out_v + B_SZ*JO;       // [256,10]

    float* s_part = (float*)d_ws;             // [128][160][256] f32; chunk0 doubles as s_sum
    float* vT0    = s_part + (size_t)NCH*JO*B_SZ;
    float* vsumT  = vT0 + JO*B_SZ;

    dim3 blk(256), gphase(NCH*NBG), gred(JO*B_SZ/256), gsq(B_SZ*C_SZ/256);

    // iter 0: uniform c (softmax of zeros = 1/10 -> pre_scale)
    caps_phase<<<gphase, blk, 0, stream>>>(u, W, nullptr, s_part, 0);
    caps_reduceA<<<gred, blk, 0, stream>>>(s_part, 0.1f);
    caps_squash<<<gsq, blk, 0, stream>>>(s_part, nullptr, vT0, nullptr, nullptr);
    // iter 1: b = uh.v0
    caps_phase<<<gphase, blk, 0, stream>>>(u, W, vT0, s_part, 1);
    caps_reduceA<<<gred, blk, 0, stream>>>(s_part, 1.0f);
    caps_squash<<<gsq, blk, 0, stream>>>(s_part, vT0, vsumT, nullptr, nullptr);
    // iter 2: b = uh.(v0+v1); final squash -> outputs
    caps_phase<<<gphase, blk, 0, stream>>>(u, W, vsumT, s_part, 1);
    caps_reduceA<<<gred, blk, 0, stream>>>(s_part, 1.0f);
    caps_squash<<<gsq, blk, 0, stream>>>(s_part, nullptr, nullptr, out_v, out_logit);
}